// Round 1
// baseline (363.524 us; speedup 1.0000x reference)
//
#include <hip/hip_runtime.h>

// Problem constants (fixed by setup_inputs): B=4, C=3, H=256, W=512, K2=121 (k=11)
#define BB 4
#define CC 3
#define HH 256
#define WW 512
#define K2 121
#define KK 11
#define HWS (HH * WW)            // 131072
#define NG  (BB * HWS / 4)       // 131072 thread-groups of 4 pixels

__global__ __launch_bounds__(256) void ff_loss_kernel(
    const float* __restrict__ img1,
    const float* __restrict__ img2,
    const float* __restrict__ ff,
    const float* __restrict__ vmask,
    float* __restrict__ out)
{
    const int tid = blockIdx.x * 256 + threadIdx.x;
    float lsum = 0.0f;

    {
        const int b   = tid >> 15;          // tid / (HWS/4), HWS/4 = 32768
        const int rem = tid & 32767;
        const int hw  = rem << 2;           // first of 4 consecutive pixels
        const int h   = hw >> 9;            // hw / W
        const int w0  = hw & 511;           // hw % W

        // ---- Phase 1: flow accumulation over K2=121 kernel taps ----
        const float4* ffp = reinterpret_cast<const float4*>(ff)
                          + (size_t)b * K2 * (HWS / 4) + (hw >> 2);
        float4 fx = make_float4(0.f, 0.f, 0.f, 0.f);
        float4 fy = make_float4(0.f, 0.f, 0.f, 0.f);
        int k = 0;
        for (int ki = 0; ki < KK; ++ki) {          // outer: 11 iters (not unrolled)
            const float yv = (float)(ki - 5);
            #pragma unroll
            for (int kj = 0; kj < KK; ++kj, ++k) { // inner: unrolled 11, keeps ~11 loads in flight
                const float xv = (float)(kj - 5);
                const float4 f = ffp[k * (HWS / 4)];
                fx.x = fmaf(f.x, xv, fx.x); fx.y = fmaf(f.y, xv, fx.y);
                fx.z = fmaf(f.z, xv, fx.z); fx.w = fmaf(f.w, xv, fx.w);
                fy.x = fmaf(f.x, yv, fy.x); fy.y = fmaf(f.y, yv, fy.y);
                fy.z = fmaf(f.z, yv, fy.z); fy.w = fmaf(f.w, yv, fy.w);
            }
        }

        const float fxa[4] = {fx.x, fx.y, fx.z, fx.w};
        const float fya[4] = {fy.x, fy.y, fy.z, fy.w};
        const float* i1b = img1  + (size_t)b * CC * HWS;
        const float* i2b = img2  + (size_t)b * CC * HWS;
        const float* vmb = vmask + (size_t)b * CC * HWS;

        // ---- Phase 2: bilinear sample + occlusion mask + Charbonnier ----
        #pragma unroll
        for (int j = 0; j < 4; ++j) {
            const int   pix = hw + j;
            const float gx  = (float)(w0 + j) + fxa[j];
            const float gy  = (float)h + fya[j];
            const float x0f = floorf(gx), y0f = floorf(gy);
            const float x1f = x0f + 1.0f, y1f = y0f + 1.0f;
            const float wx1 = gx - x0f,  wx0 = 1.0f - wx1;
            const float wy1 = gy - y0f,  wy0 = 1.0f - wy1;

            // corner validity, exactly as the reference computes it
            const float vx0 = (x0f >= 0.0f && x0f <= (float)(WW - 1)) ? 1.0f : 0.0f;
            const float vx1 = (x1f >= 0.0f && x1f <= (float)(WW - 1)) ? 1.0f : 0.0f;
            const float vy0 = (y0f >= 0.0f && y0f <= (float)(HH - 1)) ? 1.0f : 0.0f;
            const float vy1 = (y1f >= 0.0f && y1f <= (float)(HH - 1)) ? 1.0f : 0.0f;
            const float m00 = vx0 * vy0, m01 = vx1 * vy0;
            const float m10 = vx0 * vy1, m11 = vx1 * vy1;
            const float w00 = wx0 * wy0, w01 = wx1 * wy0;
            const float w10 = wx0 * wy1, w11 = wx1 * wy1;
            const float mask = m00 * w00 + m01 * w01 + m10 * w10 + m11 * w11;

            if (mask >= 0.9999f) {   // else: binary mask = 0 -> contribution exactly 0
                const int xi0 = min(max((int)x0f, 0), WW - 1);
                const int xi1 = min(max((int)x1f, 0), WW - 1);
                const int yi0 = min(max((int)y0f, 0), HH - 1);
                const int yi1 = min(max((int)y1f, 0), HH - 1);
                const int i00 = yi0 * WW + xi0, i01 = yi0 * WW + xi1;
                const int i10 = yi1 * WW + xi0, i11 = yi1 * WW + xi1;
                #pragma unroll
                for (int c = 0; c < CC; ++c) {
                    const float* ip = i1b + c * HWS;
                    const float v00 = m00 * ip[i00];
                    const float v01 = m01 * ip[i01];
                    const float v10 = m10 * ip[i10];
                    const float v11 = m11 * ip[i11];
                    const float recon = v00 * w00 + v01 * w01 + v10 * w10 + v11 * w11;
                    const float d = recon - i2b[c * HWS + pix];
                    lsum += vmb[c * HWS + pix] * sqrtf(fmaf(d, d, 1e-6f));
                }
            }
        }
    }

    // ---- Phase 3: reduction: wave shuffle -> LDS -> one atomic per block ----
    #pragma unroll
    for (int off = 32; off > 0; off >>= 1)
        lsum += __shfl_down(lsum, off, 64);

    __shared__ float ws[4];
    const int lane = threadIdx.x & 63;
    const int wid  = threadIdx.x >> 6;
    if (lane == 0) ws[wid] = lsum;
    __syncthreads();
    if (threadIdx.x == 0) {
        const float s = ws[0] + ws[1] + ws[2] + ws[3];
        atomicAdd(out, s * (1.0f / (float)(BB * CC * HH * WW)));
    }
}

extern "C" void kernel_launch(void* const* d_in, const int* in_sizes, int n_in,
                              void* d_out, int out_size, void* d_ws, size_t ws_size,
                              hipStream_t stream) {
    const float* img1 = (const float*)d_in[0];
    const float* img2 = (const float*)d_in[1];
    const float* ff   = (const float*)d_in[2];
    const float* vm   = (const float*)d_in[3];
    float* out = (float*)d_out;

    // d_out is poisoned 0xAA before every timed launch — zero it (capture-safe).
    hipMemsetAsync(out, 0, sizeof(float), stream);
    ff_loss_kernel<<<NG / 256, 256, 0, stream>>>(img1, img2, ff, vm, out);
}

// Round 2
// 357.153 us; speedup vs baseline: 1.0178x; 1.0178x over previous
//
#include <hip/hip_runtime.h>

// Problem constants (fixed by setup_inputs): B=4, C=3, H=256, W=512, K2=121 (k=11)
#define BB 4
#define CC 3
#define HH 256
#define WW 512
#define K2 121
#define KK 11
#define HWS (HH * WW)            // 131072 = 2^17
#define NT  (BB * HWS)           // 524288 threads, 1 pixel each

__global__ __launch_bounds__(256) void ff_loss_kernel(
    const float* __restrict__ img1,
    const float* __restrict__ img2,
    const float* __restrict__ ff,
    const float* __restrict__ vmask,
    float* __restrict__ out)
{
    const int tid = blockIdx.x * 256 + threadIdx.x;
    float lsum = 0.0f;

    {
        const int b  = tid >> 17;           // tid / HWS
        const int hw = tid & (HWS - 1);
        const int h  = hw >> 9;             // hw / W
        const int w  = hw & 511;            // hw % W

        // ---- Phase 1: flow accumulation over K2=121 kernel taps ----
        // 1 scalar float per thread per tap; wave reads 256 contiguous bytes.
        const float* ffp = ff + (size_t)b * K2 * HWS + hw;
        float fx = 0.0f, fy = 0.0f;
        int k = 0;
        for (int ki = 0; ki < KK; ++ki) {           // 11 outer iters
            const float yv = (float)(ki - 5);
            #pragma unroll
            for (int kj = 0; kj < KK; ++kj, ++k) {  // unrolled 11 -> 11 loads in flight
                const float f = ffp[(size_t)k * HWS];
                fx = fmaf(f, (float)(kj - 5), fx);
                fy = fmaf(f, yv, fy);
            }
        }

        // ---- Phase 2: bilinear sample + occlusion mask + Charbonnier ----
        const float* i1b = img1  + (size_t)b * CC * HWS;
        const float* i2b = img2  + (size_t)b * CC * HWS;
        const float* vmb = vmask + (size_t)b * CC * HWS;

        const float gx  = (float)w + fx;
        const float gy  = (float)h + fy;
        const float x0f = floorf(gx), y0f = floorf(gy);
        const float x1f = x0f + 1.0f, y1f = y0f + 1.0f;
        const float wx1 = gx - x0f,  wx0 = 1.0f - wx1;
        const float wy1 = gy - y0f,  wy0 = 1.0f - wy1;

        const float vx0 = (x0f >= 0.0f && x0f <= (float)(WW - 1)) ? 1.0f : 0.0f;
        const float vx1 = (x1f >= 0.0f && x1f <= (float)(WW - 1)) ? 1.0f : 0.0f;
        const float vy0 = (y0f >= 0.0f && y0f <= (float)(HH - 1)) ? 1.0f : 0.0f;
        const float vy1 = (y1f >= 0.0f && y1f <= (float)(HH - 1)) ? 1.0f : 0.0f;
        const float m00 = vx0 * vy0, m01 = vx1 * vy0;
        const float m10 = vx0 * vy1, m11 = vx1 * vy1;
        const float w00 = wx0 * wy0, w01 = wx1 * wy0;
        const float w10 = wx0 * wy1, w11 = wx1 * wy1;
        const float mask = m00 * w00 + m01 * w01 + m10 * w10 + m11 * w11;

        if (mask >= 0.9999f) {   // else: binary mask = 0 -> contribution exactly 0
            const int xi0 = min(max((int)x0f, 0), WW - 1);
            const int xi1 = min(max((int)x1f, 0), WW - 1);
            const int yi0 = min(max((int)y0f, 0), HH - 1);
            const int yi1 = min(max((int)y1f, 0), HH - 1);
            const int i00 = yi0 * WW + xi0, i01 = yi0 * WW + xi1;
            const int i10 = yi1 * WW + xi0, i11 = yi1 * WW + xi1;
            #pragma unroll
            for (int c = 0; c < CC; ++c) {
                const float* ip = i1b + c * HWS;
                const float v00 = m00 * ip[i00];
                const float v01 = m01 * ip[i01];
                const float v10 = m10 * ip[i10];
                const float v11 = m11 * ip[i11];
                const float recon = v00 * w00 + v01 * w01 + v10 * w10 + v11 * w11;
                const float d = recon - i2b[c * HWS + hw];
                lsum += vmb[c * HWS + hw] * sqrtf(fmaf(d, d, 1e-6f));
            }
        }
    }

    // ---- Phase 3: reduction: wave shuffle -> LDS -> one atomic per block ----
    #pragma unroll
    for (int off = 32; off > 0; off >>= 1)
        lsum += __shfl_down(lsum, off, 64);

    __shared__ float ws[4];
    const int lane = threadIdx.x & 63;
    const int wid  = threadIdx.x >> 6;
    if (lane == 0) ws[wid] = lsum;
    __syncthreads();
    if (threadIdx.x == 0) {
        const float s = ws[0] + ws[1] + ws[2] + ws[3];
        atomicAdd(out, s * (1.0f / (float)(BB * CC * HH * WW)));
    }
}

extern "C" void kernel_launch(void* const* d_in, const int* in_sizes, int n_in,
                              void* d_out, int out_size, void* d_ws, size_t ws_size,
                              hipStream_t stream) {
    const float* img1 = (const float*)d_in[0];
    const float* img2 = (const float*)d_in[1];
    const float* ff   = (const float*)d_in[2];
    const float* vm   = (const float*)d_in[3];
    float* out = (float*)d_out;

    // d_out is poisoned 0xAA before every timed launch — zero it (capture-safe).
    hipMemsetAsync(out, 0, sizeof(float), stream);
    ff_loss_kernel<<<NT / 256, 256, 0, stream>>>(img1, img2, ff, vm, out);
}